// Round 3
// baseline (519.960 us; speedup 1.0000x reference)
//
#include <hip/hip_runtime.h>

typedef unsigned short u16;
typedef u16   u16x8  __attribute__((ext_vector_type(8)));
typedef __bf16 bf16x8 __attribute__((ext_vector_type(8)));
typedef float f32x4  __attribute__((ext_vector_type(4)));

constexpr int BATCH  = 4;
constexpr int CDIM   = 256;
constexpr int NTOK   = 16384;   // 128*128
constexpr int INNERD = 512;

__device__ __forceinline__ u16 f2b(float f) {
  union { float f; unsigned u; } v; v.f = f;
  return (u16)((v.u + 0x7fffu + ((v.u >> 16) & 1u)) >> 16);
}
__device__ __forceinline__ float b2f(u16 b) {
  union { unsigned u; float f; } v; v.u = ((unsigned)b) << 16;
  return v.f;
}

// ---------------- transpose + convert: (b,c,n) fp32 -> (b,n,c) bf16 -------------
__global__ __launch_bounds__(256) void transpose_cvt(
    const float* __restrict__ x, const float* __restrict__ ctx,
    u16* __restrict__ xt, u16* __restrict__ ct) {
  __shared__ float tile[64][33];
  int zb = blockIdx.z;            // 0..7 : b*2 + which
  int b = zb >> 1;
  const float* src = (zb & 1) ? ctx : x;
  u16* dst = (zb & 1) ? ct : xt;
  src += (size_t)b * CDIM * NTOK;
  dst += (size_t)b * NTOK * CDIM;
  int n0 = blockIdx.x * 32, c0 = blockIdx.y * 64;
  int tx = threadIdx.x & 31, ty = threadIdx.x >> 5;   // ty 0..7
#pragma unroll
  for (int i = 0; i < 64; i += 8)
    tile[ty + i][tx] = src[(size_t)(c0 + ty + i) * NTOK + n0 + tx];
  __syncthreads();
  int nl = threadIdx.x >> 3;          // 0..31
  int cl = (threadIdx.x & 7) * 8;     // 0..56
  u16x8 o;
#pragma unroll
  for (int j = 0; j < 8; j++) o[j] = f2b(tile[cl + j][nl]);
  *(u16x8*)&dst[(size_t)(n0 + nl) * CDIM + c0 + cl] = o;
}

// ---------------- weight transpose: (256,512) fp32 -> (512,256) bf16 ------------
__global__ __launch_bounds__(256) void wtrans(
    const float* __restrict__ Wq, const float* __restrict__ Wk,
    u16* __restrict__ qt, u16* __restrict__ kt) {
  __shared__ float tile[32][33];
  const float* src = blockIdx.z == 0 ? Wq : Wk;
  u16* dst = blockIdx.z == 0 ? qt : kt;
  int i0 = blockIdx.x * 32, c0 = blockIdx.y * 32;
  int tx = threadIdx.x & 31, ty = threadIdx.x >> 5;
#pragma unroll
  for (int r = 0; r < 32; r += 8)
    tile[ty + r][tx] = src[(size_t)(c0 + ty + r) * INNERD + i0 + tx];
  __syncthreads();
#pragma unroll
  for (int r = 0; r < 32; r += 8)
    dst[(size_t)(i0 + ty + r) * CDIM + c0 + tx] = f2b(tile[tx][ty + r]);
}

// ---------------- k projection GEMM + fused exp/rowsum -------------------------
// expk[b][i][n] = exp(sum_c Wk[c][i]*ctx[b][c][n]);  ksum[b][i] += row sums
#define MT 128
#define NT 128
#define KB 64
#define LDK 72   // 64 + 8 pad (144 B rows, 16B-aligned)

__global__ __launch_bounds__(256) void kproj_gemm(
    const u16* __restrict__ Wkt, const u16* __restrict__ ctx_bt,
    u16* __restrict__ expk, float* __restrict__ ksum) {
  int b = blockIdx.z;
  const u16* A  = Wkt;
  const u16* Bt = ctx_bt + (size_t)b * NTOK * CDIM;
  u16* Out = expk + (size_t)b * INNERD * NTOK;
  int i0 = blockIdx.x * MT;
  int n0 = blockIdx.y * NT;

  __shared__ __align__(16) u16 As[MT * LDK];
  __shared__ __align__(16) u16 Bs[NT * LDK];

  int tid = threadIdx.x;
  int wave = tid >> 6, lane = tid & 63;
  int wm = (wave >> 1) * 64, wn = (wave & 1) * 64;
  int quad = lane >> 4, l16 = lane & 15;

  f32x4 acc[4][4];
#pragma unroll
  for (int i = 0; i < 4; i++)
#pragma unroll
    for (int j = 0; j < 4; j++) acc[i][j] = (f32x4)(0.0f);

  for (int k0 = 0; k0 < CDIM; k0 += KB) {
    __syncthreads();
#pragma unroll
    for (int q = tid; q < MT * (KB / 8); q += 256) {
      int row = q >> 3, kc = (q & 7) * 8;
      *(u16x8*)&As[row * LDK + kc] = *(const u16x8*)&A[(size_t)(i0 + row) * CDIM + k0 + kc];
    }
#pragma unroll
    for (int q = tid; q < NT * (KB / 8); q += 256) {
      int row = q >> 3, kc = (q & 7) * 8;
      *(u16x8*)&Bs[row * LDK + kc] = *(const u16x8*)&Bt[(size_t)(n0 + row) * CDIM + k0 + kc];
    }
    __syncthreads();
#pragma unroll
    for (int kk = 0; kk < KB; kk += 32) {
      int ko = kk + quad * 8;
      bf16x8 af[4], bfr[4];
#pragma unroll
      for (int m = 0; m < 4; m++)
        af[m] = __builtin_bit_cast(bf16x8, *(const u16x8*)&As[(wm + m * 16 + l16) * LDK + ko]);
#pragma unroll
      for (int e = 0; e < 4; e++)
        bfr[e] = __builtin_bit_cast(bf16x8, *(const u16x8*)&Bs[(wn + e * 16 + l16) * LDK + ko]);
#pragma unroll
      for (int m = 0; m < 4; m++)
#pragma unroll
        for (int e = 0; e < 4; e++)
          acc[m][e] = __builtin_amdgcn_mfma_f32_16x16x32_bf16(af[m], bfr[e], acc[m][e], 0, 0, 0);
    }
  }

  float* ksb = ksum + (size_t)b * INNERD;
#pragma unroll
  for (int m = 0; m < 4; m++) {
    float rs[4] = {0.f, 0.f, 0.f, 0.f};
#pragma unroll
    for (int e = 0; e < 4; e++) {
      int col = n0 + wn + e * 16 + l16;
#pragma unroll
      for (int r = 0; r < 4; r++) {
        float ev = __expf(acc[m][e][r]);
        Out[(size_t)(i0 + wm + m * 16 + quad * 4 + r) * NTOK + col] = f2b(ev);
        rs[r] += ev;
      }
    }
#pragma unroll
    for (int off = 1; off < 16; off <<= 1)
#pragma unroll
      for (int r = 0; r < 4; r++) rs[r] += __shfl_xor(rs[r], off, 64);
    if (l16 == 0)
#pragma unroll
      for (int r = 0; r < 4; r++)
        atomicAdd(&ksb[i0 + wm + m * 16 + quad * 4 + r], rs[r]);
  }
}

// ---------------- zero scratch -------------------------------------------------
__global__ void zero_f32(float* p, int nelem) {
  int i = blockIdx.x * blockDim.x + threadIdx.x;
  if (i < nelem) p[i] = 0.0f;
}

// ---------------- T[b][d][c] = sum_n expk[b][d][n] * ctx[b][c][n] --------------
// A = expk (bf16, n-contig), B = ctx (fp32, n-contig), split-K over n segments.
#define NSEG 8
__global__ __launch_bounds__(256) void tgemm(
    const u16* __restrict__ expk, const float* __restrict__ ctx,
    float* __restrict__ T) {
  int z = blockIdx.z;             // b * NSEG + seg
  int b = z / NSEG, seg = z % NSEG;
  int d0 = blockIdx.x * MT;       // 0..3 * 128
  int c0 = blockIdx.y * NT;       // 0..1 * 128
  const u16* Ab = expk + (size_t)b * INNERD * NTOK + (size_t)d0 * NTOK;
  const float* Bb = ctx + (size_t)b * CDIM * NTOK + (size_t)c0 * NTOK;
  size_t nb = (size_t)seg * (NTOK / NSEG);   // 2048-token segment

  __shared__ __align__(16) u16 As[MT * LDK];
  __shared__ __align__(16) u16 Bs[NT * LDK];

  int tid = threadIdx.x;
  int wave = tid >> 6, lane = tid & 63;
  int wm = (wave >> 1) * 64, wn = (wave & 1) * 64;
  int quad = lane >> 4, l16 = lane & 15;

  f32x4 acc[4][4];
#pragma unroll
  for (int i = 0; i < 4; i++)
#pragma unroll
    for (int j = 0; j < 4; j++) acc[i][j] = (f32x4)(0.0f);

  for (int kt = 0; kt < NTOK / NSEG; kt += KB) {
    __syncthreads();
#pragma unroll
    for (int q = tid; q < MT * (KB / 8); q += 256) {
      int row = q >> 3, kc = (q & 7) * 8;
      *(u16x8*)&As[row * LDK + kc] = *(const u16x8*)&Ab[(size_t)row * NTOK + nb + kt + kc];
    }
#pragma unroll
    for (int q = tid; q < NT * (KB / 8); q += 256) {
      int row = q >> 3, kc = (q & 7) * 8;
      const float* src = &Bb[(size_t)row * NTOK + nb + kt + kc];
      f32x4 f0 = *(const f32x4*)src;
      f32x4 f1 = *(const f32x4*)(src + 4);
      u16x8 o;
#pragma unroll
      for (int t = 0; t < 4; t++) { o[t] = f2b(f0[t]); o[t + 4] = f2b(f1[t]); }
      *(u16x8*)&Bs[row * LDK + kc] = o;
    }
    __syncthreads();
#pragma unroll
    for (int kk = 0; kk < KB; kk += 32) {
      int ko = kk + quad * 8;
      bf16x8 af[4], bfr[4];
#pragma unroll
      for (int m = 0; m < 4; m++)
        af[m] = __builtin_bit_cast(bf16x8, *(const u16x8*)&As[(wm + m * 16 + l16) * LDK + ko]);
#pragma unroll
      for (int e = 0; e < 4; e++)
        bfr[e] = __builtin_bit_cast(bf16x8, *(const u16x8*)&Bs[(wn + e * 16 + l16) * LDK + ko]);
#pragma unroll
      for (int m = 0; m < 4; m++)
#pragma unroll
        for (int e = 0; e < 4; e++)
          acc[m][e] = __builtin_amdgcn_mfma_f32_16x16x32_bf16(af[m], bfr[e], acc[m][e], 0, 0, 0);
    }
  }

  float* Tb = T + (size_t)b * INNERD * CDIM;
#pragma unroll
  for (int m = 0; m < 4; m++) {
    int rowb = d0 + wm + m * 16 + quad * 4;
#pragma unroll
    for (int e = 0; e < 4; e++) {
      int col = c0 + wn + e * 16 + l16;
#pragma unroll
      for (int r = 0; r < 4; r++)
        atomicAdd(&Tb[(size_t)(rowb + r) * CDIM + col], acc[m][e][r]);
    }
  }
}

// ------- weff[b][i=h*64+d][c] = (sum_e (sum_c' T[i][c']Wv[c'][h64+e]) Wo[h64+e][c]) / ksum
__global__ __launch_bounds__(256) void cmweff_k(
    const float* __restrict__ T, const float* __restrict__ Wv,
    const float* __restrict__ Wo, const float* __restrict__ ksum,
    float* __restrict__ weff) {
  int bi = blockIdx.x;            // 0..2047
  int b = bi >> 9, i = bi & 511, h = i >> 6;
  __shared__ float Trow[256];
  __shared__ float cmrow[64];
  Trow[threadIdx.x] = T[((size_t)b * INNERD + i) * CDIM + threadIdx.x];
  __syncthreads();
  if (threadIdx.x < 64) {
    float s = 0.0f;
#pragma unroll 8
    for (int c = 0; c < 256; c++) s += Trow[c] * Wv[(size_t)c * INNERD + h * 64 + threadIdx.x];
    cmrow[threadIdx.x] = s;
  }
  __syncthreads();
  float inv = 1.0f / ksum[(size_t)b * INNERD + i];
  int c = threadIdx.x;
  float s = 0.0f;
#pragma unroll 8
  for (int e = 0; e < 64; e++) s += cmrow[e] * Wo[(size_t)(h * 64 + e) * CDIM + c];
  weff[(size_t)bi * CDIM + c] = s * inv;
}

// ---------------- Gt[b][c][c'] = sum_i weff[b][i][c] * Wq_t[i][c']  (bf16) -----
__global__ __launch_bounds__(256) void gt_k(
    const float* __restrict__ weff, const u16* __restrict__ Wq_t, u16* __restrict__ Gt) {
  int bc = blockIdx.x;            // 0..1023
  int b = bc >> 8, c = bc & 255;
  __shared__ float ws[512];
  for (int j = threadIdx.x; j < 512; j += 256)
    ws[j] = weff[((size_t)b * 512 + j) * CDIM + c];
  __syncthreads();
  int cp = threadIdx.x;
  float s = 0.0f;
#pragma unroll 8
  for (int i = 0; i < 512; i++) s += ws[i] * b2f(Wq_t[(size_t)i * CDIM + cp]);
  Gt[(size_t)bc * CDIM + cp] = f2b(s);
}

// ---------------- final: out[b][c][n] = x + bo[c] + sum_c' Gt[c][c'] x_bt[n][c']
__global__ __launch_bounds__(256) void final_gemm(
    const u16* __restrict__ Gt, const u16* __restrict__ x_bt,
    const float* __restrict__ x, const float* __restrict__ bo,
    float* __restrict__ out) {
  int b = blockIdx.z;
  const u16* A  = Gt + (size_t)b * CDIM * CDIM;
  const u16* Bt = x_bt + (size_t)b * NTOK * CDIM;
  const float* xb = x + (size_t)b * CDIM * NTOK;
  float* ob = out + (size_t)b * CDIM * NTOK;
  int i0 = blockIdx.x * MT;       // 0 or 128
  int n0 = blockIdx.y * NT;

  __shared__ __align__(16) u16 As[MT * LDK];
  __shared__ __align__(16) u16 Bs[NT * LDK];

  int tid = threadIdx.x;
  int wave = tid >> 6, lane = tid & 63;
  int wm = (wave >> 1) * 64, wn = (wave & 1) * 64;
  int quad = lane >> 4, l16 = lane & 15;

  f32x4 acc[4][4];
#pragma unroll
  for (int i = 0; i < 4; i++)
#pragma unroll
    for (int j = 0; j < 4; j++) acc[i][j] = (f32x4)(0.0f);

  for (int k0 = 0; k0 < CDIM; k0 += KB) {
    __syncthreads();
#pragma unroll
    for (int q = tid; q < MT * (KB / 8); q += 256) {
      int row = q >> 3, kc = (q & 7) * 8;
      *(u16x8*)&As[row * LDK + kc] = *(const u16x8*)&A[(size_t)(i0 + row) * CDIM + k0 + kc];
    }
#pragma unroll
    for (int q = tid; q < NT * (KB / 8); q += 256) {
      int row = q >> 3, kc = (q & 7) * 8;
      *(u16x8*)&Bs[row * LDK + kc] = *(const u16x8*)&Bt[(size_t)(n0 + row) * CDIM + k0 + kc];
    }
    __syncthreads();
#pragma unroll
    for (int kk = 0; kk < KB; kk += 32) {
      int ko = kk + quad * 8;
      bf16x8 af[4], bfr[4];
#pragma unroll
      for (int m = 0; m < 4; m++)
        af[m] = __builtin_bit_cast(bf16x8, *(const u16x8*)&As[(wm + m * 16 + l16) * LDK + ko]);
#pragma unroll
      for (int e = 0; e < 4; e++)
        bfr[e] = __builtin_bit_cast(bf16x8, *(const u16x8*)&Bs[(wn + e * 16 + l16) * LDK + ko]);
#pragma unroll
      for (int m = 0; m < 4; m++)
#pragma unroll
        for (int e = 0; e < 4; e++)
          acc[m][e] = __builtin_amdgcn_mfma_f32_16x16x32_bf16(af[m], bfr[e], acc[m][e], 0, 0, 0);
    }
  }
#pragma unroll
  for (int m = 0; m < 4; m++) {
    int rowb = i0 + wm + m * 16 + quad * 4;
#pragma unroll
    for (int e = 0; e < 4; e++) {
      int col = n0 + wn + e * 16 + l16;
#pragma unroll
      for (int r = 0; r < 4; r++) {
        int c = rowb + r;
        ob[(size_t)c * NTOK + col] = acc[m][e][r] + xb[(size_t)c * NTOK + col] + bo[c];
      }
    }
  }
}

extern "C" void kernel_launch(void* const* d_in, const int* in_sizes, int n_in,
                              void* d_out, int out_size, void* d_ws, size_t ws_size,
                              hipStream_t stream) {
  const float* x   = (const float*)d_in[0];
  const float* ctx = (const float*)d_in[1];
  const float* Wq  = (const float*)d_in[2];
  const float* Wk  = (const float*)d_in[3];
  const float* Wv  = (const float*)d_in[4];
  const float* Wo  = (const float*)d_in[5];
  const float* bo  = (const float*)d_in[6];
  float* out = (float*)d_out;

  char* ws = (char*)d_ws;
  u16* ctx_bt = (u16*)ws;  ws += (size_t)BATCH * NTOK * CDIM * 2;     // 32 MiB
  u16* x_bt   = (u16*)ws;  ws += (size_t)BATCH * NTOK * CDIM * 2;     // 32 MiB
  u16* Wq_t   = (u16*)ws;  ws += (size_t)INNERD * CDIM * 2;
  u16* Wk_t   = (u16*)ws;  ws += (size_t)INNERD * CDIM * 2;
  u16* expk   = (u16*)ws;  ws += (size_t)BATCH * INNERD * NTOK * 2;   // 64 MiB
  float* T    = (float*)ws; ws += (size_t)BATCH * INNERD * CDIM * 4;  // 2 MiB
  float* ksum = (float*)ws; ws += (size_t)BATCH * INNERD * 4;         // 8 KiB (contiguous after T)
  float* weff = (float*)ws; ws += (size_t)BATCH * INNERD * CDIM * 4;  // 2 MiB
  u16* Gt     = (u16*)ws;  ws += (size_t)BATCH * CDIM * CDIM * 2;

  const int nzero = BATCH * INNERD * CDIM + BATCH * INNERD;  // T + ksum

  transpose_cvt<<<dim3(NTOK / 32, CDIM / 64, BATCH * 2), 256, 0, stream>>>(x, ctx, x_bt, ctx_bt);
  wtrans<<<dim3(INNERD / 32, CDIM / 32, 2), 256, 0, stream>>>(Wq, Wk, Wq_t, Wk_t);
  zero_f32<<<(nzero + 255) / 256, 256, 0, stream>>>(T, nzero);
  kproj_gemm<<<dim3(INNERD / MT, NTOK / NT, BATCH), 256, 0, stream>>>(Wk_t, ctx_bt, expk, ksum);
  tgemm<<<dim3(INNERD / MT, CDIM / NT, BATCH * NSEG), 256, 0, stream>>>(expk, ctx, T);
  cmweff_k<<<BATCH * INNERD, 256, 0, stream>>>(T, Wv, Wo, ksum, weff);
  gt_k<<<BATCH * CDIM, 256, 0, stream>>>(weff, Wq_t, Gt);
  final_gemm<<<dim3(CDIM / MT, NTOK / NT, BATCH), 256, 0, stream>>>(Gt, x_bt, x, bo, out);
}

// Round 4
// 397.806 us; speedup vs baseline: 1.3071x; 1.3071x over previous
//
#include <hip/hip_runtime.h>

typedef unsigned short u16;
typedef u16   u16x8  __attribute__((ext_vector_type(8)));
typedef __bf16 bf16x8 __attribute__((ext_vector_type(8)));
typedef float f32x4  __attribute__((ext_vector_type(4)));

constexpr int BATCH  = 4;
constexpr int CDIM   = 256;
constexpr int NTOK   = 16384;   // 128*128
constexpr int INNERD = 512;

__device__ __forceinline__ u16 f2b(float f) {
  union { float f; unsigned u; } v; v.f = f;
  return (u16)((v.u + 0x7fffu + ((v.u >> 16) & 1u)) >> 16);
}
__device__ __forceinline__ float b2f(u16 b) {
  union { unsigned u; float f; } v; v.u = ((unsigned)b) << 16;
  return v.f;
}

// ---------------- transpose + convert: (b,c,n) fp32 -> (b,n,c) bf16 -------------
__global__ __launch_bounds__(256) void transpose_cvt(
    const float* __restrict__ x, const float* __restrict__ ctx,
    u16* __restrict__ xt, u16* __restrict__ ct) {
  __shared__ float tile[64][33];
  int zb = blockIdx.z;            // 0..7 : b*2 + which
  int b = zb >> 1;
  const float* src = (zb & 1) ? ctx : x;
  u16* dst = (zb & 1) ? ct : xt;
  src += (size_t)b * CDIM * NTOK;
  dst += (size_t)b * NTOK * CDIM;
  int n0 = blockIdx.x * 32, c0 = blockIdx.y * 64;
  int tx = threadIdx.x & 31, ty = threadIdx.x >> 5;   // ty 0..7
#pragma unroll
  for (int i = 0; i < 64; i += 8)
    tile[ty + i][tx] = src[(size_t)(c0 + ty + i) * NTOK + n0 + tx];
  __syncthreads();
  int nl = threadIdx.x >> 3;          // 0..31
  int cl = (threadIdx.x & 7) * 8;     // 0..56
  u16x8 o;
#pragma unroll
  for (int j = 0; j < 8; j++) o[j] = f2b(tile[cl + j][nl]);
  *(u16x8*)&dst[(size_t)(n0 + nl) * CDIM + c0 + cl] = o;
}

// ---------------- weight transpose: (256,512) fp32 -> (512,256) bf16 ------------
__global__ __launch_bounds__(256) void wtrans(
    const float* __restrict__ Wq, const float* __restrict__ Wk, const float* __restrict__ Wv,
    u16* __restrict__ qt, u16* __restrict__ kt, u16* __restrict__ vt) {
  __shared__ float tile[32][33];
  const float* src = blockIdx.z == 0 ? Wq : (blockIdx.z == 1 ? Wk : Wv);
  u16* dst = blockIdx.z == 0 ? qt : (blockIdx.z == 1 ? kt : vt);
  int i0 = blockIdx.x * 32, c0 = blockIdx.y * 32;
  int tx = threadIdx.x & 31, ty = threadIdx.x >> 5;
#pragma unroll
  for (int r = 0; r < 32; r += 8)
    tile[ty + r][tx] = src[(size_t)(c0 + ty + r) * INNERD + i0 + tx];
  __syncthreads();
#pragma unroll
  for (int r = 0; r < 32; r += 8)
    dst[(size_t)(i0 + ty + r) * CDIM + c0 + tx] = f2b(tile[tx][ty + r]);
}

// ---------------- projection GEMM (r1 structure) -------------------------------
// K-half: ktb[b][i][n] = exp(sum_c Wk[c][i]*ctx[b][c][n])
// V-half: vtb[b][i][n] =      sum_c Wv[c][i]*ctx[b][c][n]
#define MT 128
#define NT 128
#define KB 64
#define LDK 72   // 64 + 8 pad

__global__ __launch_bounds__(256) void proj_gemm(
    const u16* __restrict__ Wkt, const u16* __restrict__ Wvt,
    const u16* __restrict__ ctx_bt, u16* __restrict__ ktp, u16* __restrict__ vtp) {
  int z = blockIdx.z;             // 0..7
  int b = z >> 1;
  bool isK = !(z & 1);
  const u16* A  = isK ? Wkt : Wvt;
  const u16* Bt = ctx_bt + (size_t)b * NTOK * CDIM;
  u16* Out = (isK ? ktp : vtp) + (size_t)b * INNERD * NTOK;
  int i0 = blockIdx.x * MT;
  int n0 = blockIdx.y * NT;

  __shared__ __align__(16) u16 As[MT * LDK];
  __shared__ __align__(16) u16 Bs[NT * LDK];

  int tid = threadIdx.x;
  int wave = tid >> 6, lane = tid & 63;
  int wm = (wave >> 1) * 64, wn = (wave & 1) * 64;
  int quad = lane >> 4, l16 = lane & 15;

  f32x4 acc[4][4];
#pragma unroll
  for (int i = 0; i < 4; i++)
#pragma unroll
    for (int j = 0; j < 4; j++) acc[i][j] = (f32x4)(0.0f);

  for (int k0 = 0; k0 < CDIM; k0 += KB) {
    __syncthreads();
#pragma unroll
    for (int q = tid; q < MT * (KB / 8); q += 256) {
      int row = q >> 3, kc = (q & 7) * 8;
      *(u16x8*)&As[row * LDK + kc] = *(const u16x8*)&A[(size_t)(i0 + row) * CDIM + k0 + kc];
    }
#pragma unroll
    for (int q = tid; q < NT * (KB / 8); q += 256) {
      int row = q >> 3, kc = (q & 7) * 8;
      *(u16x8*)&Bs[row * LDK + kc] = *(const u16x8*)&Bt[(size_t)(n0 + row) * CDIM + k0 + kc];
    }
    __syncthreads();
#pragma unroll
    for (int kk = 0; kk < KB; kk += 32) {
      int ko = kk + quad * 8;
      bf16x8 af[4], bfr[4];
#pragma unroll
      for (int m = 0; m < 4; m++)
        af[m] = __builtin_bit_cast(bf16x8, *(const u16x8*)&As[(wm + m * 16 + l16) * LDK + ko]);
#pragma unroll
      for (int e = 0; e < 4; e++)
        bfr[e] = __builtin_bit_cast(bf16x8, *(const u16x8*)&Bs[(wn + e * 16 + l16) * LDK + ko]);
#pragma unroll
      for (int m = 0; m < 4; m++)
#pragma unroll
        for (int e = 0; e < 4; e++)
          acc[m][e] = __builtin_amdgcn_mfma_f32_16x16x32_bf16(af[m], bfr[e], acc[m][e], 0, 0, 0);
    }
  }
#pragma unroll
  for (int m = 0; m < 4; m++) {
    int rowb = i0 + wm + m * 16 + quad * 4;
#pragma unroll
    for (int e = 0; e < 4; e++) {
      int col = n0 + wn + e * 16 + l16;
#pragma unroll
      for (int r = 0; r < 4; r++) {
        float v = acc[m][e][r];
        if (isK) v = __expf(v);          // block-uniform branch
        Out[(size_t)(rowb + r) * NTOK + col] = f2b(v);
      }
    }
  }
}

// ---------------- zero scratch -------------------------------------------------
__global__ void zero_f32(float* p, int nelem) {
  int i = blockIdx.x * blockDim.x + threadIdx.x;
  if (i < nelem) p[i] = 0.0f;
}

// ------- cm[b,h][d][e] = sum_n expk[d][n] * v[e][n]; ksum[b][h*64+d] = sum_n expk
#define CM_CHUNK 2048
__global__ __launch_bounds__(256) void ctx_mat(
    const u16* __restrict__ ktp, const u16* __restrict__ vtp,
    float* __restrict__ cm, float* __restrict__ ksum) {
  int bh = blockIdx.x;            // 0..31
  int b = bh >> 3, h = bh & 7;
  const u16* Ak = ktp + ((size_t)b * INNERD + h * 64) * NTOK;
  const u16* Av = vtp + ((size_t)b * INNERD + h * 64) * NTOK;
  int tid = threadIdx.x, wave = tid >> 6, lane = tid & 63;
  int quad = lane >> 4, l16 = lane & 15;
  size_t nb = (size_t)blockIdx.y * CM_CHUNK + wave * (CM_CHUNK / 4);

  u16x8 ov;
#pragma unroll
  for (int t = 0; t < 8; t++) ov[t] = 0x3f80;      // bf16 1.0
  const bf16x8 ones = __builtin_bit_cast(bf16x8, ov);

  f32x4 acc[4][4];
  f32x4 accS[4];
#pragma unroll
  for (int i = 0; i < 4; i++) {
    accS[i] = (f32x4)(0.0f);
#pragma unroll
    for (int j = 0; j < 4; j++) acc[i][j] = (f32x4)(0.0f);
  }

  for (int n = 0; n < CM_CHUNK / 4; n += 32) {
    size_t col = nb + n + quad * 8;
    bf16x8 a[4], vv[4];
#pragma unroll
    for (int m = 0; m < 4; m++)
      a[m] = __builtin_bit_cast(bf16x8, *(const u16x8*)&Ak[(size_t)(m * 16 + l16) * NTOK + col]);
#pragma unroll
    for (int e = 0; e < 4; e++)
      vv[e] = __builtin_bit_cast(bf16x8, *(const u16x8*)&Av[(size_t)(e * 16 + l16) * NTOK + col]);
#pragma unroll
    for (int m = 0; m < 4; m++) {
      accS[m] = __builtin_amdgcn_mfma_f32_16x16x32_bf16(a[m], ones, accS[m], 0, 0, 0);
#pragma unroll
      for (int e = 0; e < 4; e++)
        acc[m][e] = __builtin_amdgcn_mfma_f32_16x16x32_bf16(a[m], vv[e], acc[m][e], 0, 0, 0);
    }
  }

  __shared__ float red[64 * 64];
  __shared__ float redS[64];
  for (int w = 0; w < 4; w++) {
    if (wave == w) {
#pragma unroll
      for (int m = 0; m < 4; m++)
#pragma unroll
        for (int e = 0; e < 4; e++)
#pragma unroll
          for (int r = 0; r < 4; r++) {
            int d = m * 16 + quad * 4 + r, ee = e * 16 + l16;
            if (w == 0) red[d * 64 + ee] = acc[m][e][r];
            else        red[d * 64 + ee] += acc[m][e][r];
          }
      if (l16 == 0) {
#pragma unroll
        for (int m = 0; m < 4; m++)
#pragma unroll
          for (int r = 0; r < 4; r++) {
            int d = m * 16 + quad * 4 + r;
            if (w == 0) redS[d] = accS[m][r];
            else        redS[d] += accS[m][r];
          }
      }
    }
    __syncthreads();
  }
  float* cmp = cm + (size_t)bh * 64 * 64;
#pragma unroll
  for (int j = tid; j < 4096; j += 256) atomicAdd(&cmp[j], red[j]);
  if (tid < 64) atomicAdd(&ksum[(size_t)b * INNERD + h * 64 + tid], redS[tid]);
}

// ---------------- weff[b][i=h*64+d][c] = (sum_e cm[d][e]*Wo[h*64+e][c])/ksum ---
__global__ __launch_bounds__(256) void weff_k(
    const float* __restrict__ cm, const float* __restrict__ Wo,
    const float* __restrict__ ksum, float* __restrict__ weff) {
  int bi = blockIdx.x;            // 0..2047
  int b = bi >> 9, i = bi & 511, h = i >> 6, d = i & 63;
  const float* cmr = cm + ((size_t)(b * 8 + h) * 64 + d) * 64;
  __shared__ float cs[64];
  if (threadIdx.x < 64) cs[threadIdx.x] = cmr[threadIdx.x];
  __syncthreads();
  float inv = 1.0f / ksum[(size_t)b * INNERD + i];
  int c = threadIdx.x;
  float s = 0.0f;
#pragma unroll 8
  for (int e = 0; e < 64; e++) s += cs[e] * Wo[(size_t)(h * 64 + e) * CDIM + c];
  weff[(size_t)bi * CDIM + c] = s * inv;
}

// ---------------- Gt[b][c][c'] = sum_i weff[b][i][c] * Wq_t[i][c']  (bf16) -----
__global__ __launch_bounds__(256) void gt_k(
    const float* __restrict__ weff, const u16* __restrict__ Wq_t, u16* __restrict__ Gt) {
  int bc = blockIdx.x;            // 0..1023
  int b = bc >> 8, c = bc & 255;
  __shared__ float ws[512];
  for (int j = threadIdx.x; j < 512; j += 256)
    ws[j] = weff[((size_t)b * 512 + j) * CDIM + c];
  __syncthreads();
  int cp = threadIdx.x;
  float s = 0.0f;
#pragma unroll 8
  for (int i = 0; i < 512; i++) s += ws[i] * b2f(Wq_t[(size_t)i * CDIM + cp]);
  Gt[(size_t)bc * CDIM + cp] = f2b(s);
}

// ---------------- final: out[b][c][n] = x + bo[c] + sum_c' Gt[c][c'] x_bt[n][c']
__global__ __launch_bounds__(256) void final_gemm(
    const u16* __restrict__ Gt, const u16* __restrict__ x_bt,
    const float* __restrict__ x, const float* __restrict__ bo,
    float* __restrict__ out) {
  int b = blockIdx.z;
  const u16* A  = Gt + (size_t)b * CDIM * CDIM;
  const u16* Bt = x_bt + (size_t)b * NTOK * CDIM;
  const float* xb = x + (size_t)b * CDIM * NTOK;
  float* ob = out + (size_t)b * CDIM * NTOK;
  int i0 = blockIdx.x * MT;       // 0 or 128
  int n0 = blockIdx.y * NT;

  __shared__ __align__(16) u16 As[MT * LDK];
  __shared__ __align__(16) u16 Bs[NT * LDK];

  int tid = threadIdx.x;
  int wave = tid >> 6, lane = tid & 63;
  int wm = (wave >> 1) * 64, wn = (wave & 1) * 64;
  int quad = lane >> 4, l16 = lane & 15;

  f32x4 acc[4][4];
#pragma unroll
  for (int i = 0; i < 4; i++)
#pragma unroll
    for (int j = 0; j < 4; j++) acc[i][j] = (f32x4)(0.0f);

  for (int k0 = 0; k0 < CDIM; k0 += KB) {
    __syncthreads();
#pragma unroll
    for (int q = tid; q < MT * (KB / 8); q += 256) {
      int row = q >> 3, kc = (q & 7) * 8;
      *(u16x8*)&As[row * LDK + kc] = *(const u16x8*)&A[(size_t)(i0 + row) * CDIM + k0 + kc];
    }
#pragma unroll
    for (int q = tid; q < NT * (KB / 8); q += 256) {
      int row = q >> 3, kc = (q & 7) * 8;
      *(u16x8*)&Bs[row * LDK + kc] = *(const u16x8*)&Bt[(size_t)(n0 + row) * CDIM + k0 + kc];
    }
    __syncthreads();
#pragma unroll
    for (int kk = 0; kk < KB; kk += 32) {
      int ko = kk + quad * 8;
      bf16x8 af[4], bfr[4];
#pragma unroll
      for (int m = 0; m < 4; m++)
        af[m] = __builtin_bit_cast(bf16x8, *(const u16x8*)&As[(wm + m * 16 + l16) * LDK + ko]);
#pragma unroll
      for (int e = 0; e < 4; e++)
        bfr[e] = __builtin_bit_cast(bf16x8, *(const u16x8*)&Bs[(wn + e * 16 + l16) * LDK + ko]);
#pragma unroll
      for (int m = 0; m < 4; m++)
#pragma unroll
        for (int e = 0; e < 4; e++)
          acc[m][e] = __builtin_amdgcn_mfma_f32_16x16x32_bf16(af[m], bfr[e], acc[m][e], 0, 0, 0);
    }
  }
#pragma unroll
  for (int m = 0; m < 4; m++) {
    int rowb = i0 + wm + m * 16 + quad * 4;
#pragma unroll
    for (int e = 0; e < 4; e++) {
      int col = n0 + wn + e * 16 + l16;
#pragma unroll
      for (int r = 0; r < 4; r++) {
        int c = rowb + r;
        ob[(size_t)c * NTOK + col] = acc[m][e][r] + xb[(size_t)c * NTOK + col] + bo[c];
      }
    }
  }
}

extern "C" void kernel_launch(void* const* d_in, const int* in_sizes, int n_in,
                              void* d_out, int out_size, void* d_ws, size_t ws_size,
                              hipStream_t stream) {
  const float* x   = (const float*)d_in[0];
  const float* ctx = (const float*)d_in[1];
  const float* Wq  = (const float*)d_in[2];
  const float* Wk  = (const float*)d_in[3];
  const float* Wv  = (const float*)d_in[4];
  const float* Wo  = (const float*)d_in[5];
  const float* bo  = (const float*)d_in[6];
  float* out = (float*)d_out;

  char* ws = (char*)d_ws;
  u16* ctx_bt = (u16*)ws;  ws += (size_t)BATCH * NTOK * CDIM * 2;     // 32 MiB
  u16* x_bt   = (u16*)ws;  ws += (size_t)BATCH * NTOK * CDIM * 2;     // 32 MiB
  u16* Wq_t   = (u16*)ws;  ws += (size_t)INNERD * CDIM * 2;
  u16* Wk_t   = (u16*)ws;  ws += (size_t)INNERD * CDIM * 2;
  u16* Wv_t   = (u16*)ws;  ws += (size_t)INNERD * CDIM * 2;
  u16* ktb    = (u16*)ws;  ws += (size_t)BATCH * INNERD * NTOK * 2;   // 64 MiB (holds exp(k))
  u16* vtb    = (u16*)ws;  ws += (size_t)BATCH * INNERD * NTOK * 2;   // 64 MiB
  float* cm   = (float*)ws; ws += (size_t)BATCH * 8 * 64 * 64 * 4;    // 512 KiB
  float* ksum = (float*)ws; ws += (size_t)BATCH * INNERD * 4;         // 8 KiB (contiguous after cm)
  float* weff = (float*)ws; ws += (size_t)BATCH * INNERD * CDIM * 4;  // 2 MiB
  u16* Gt     = (u16*)ws;  ws += (size_t)BATCH * CDIM * CDIM * 2;

  const int nzero = BATCH * 8 * 64 * 64 + BATCH * INNERD;  // cm + ksum

  transpose_cvt<<<dim3(NTOK / 32, CDIM / 64, BATCH * 2), 256, 0, stream>>>(x, ctx, x_bt, ctx_bt);
  wtrans<<<dim3(INNERD / 32, CDIM / 32, 3), 256, 0, stream>>>(Wq, Wk, Wv, Wq_t, Wk_t, Wv_t);
  zero_f32<<<(nzero + 255) / 256, 256, 0, stream>>>(cm, nzero);
  proj_gemm<<<dim3(INNERD / MT, NTOK / NT, BATCH * 2), 256, 0, stream>>>(Wk_t, Wv_t, ctx_bt, ktb, vtb);
  ctx_mat<<<dim3(BATCH * 8, NTOK / CM_CHUNK), 256, 0, stream>>>(ktb, vtb, cm, ksum);
  weff_k<<<BATCH * INNERD, 256, 0, stream>>>(cm, Wo, ksum, weff);
  gt_k<<<BATCH * CDIM, 256, 0, stream>>>(weff, Wq_t, Gt);
  final_gemm<<<dim3(CDIM / MT, NTOK / NT, BATCH), 256, 0, stream>>>(Gt, x_bt, x, bo, out);
}